// Round 10
// baseline (49.074 us; speedup 1.0000x reference)
//
#include <hip/hip_runtime.h>

// Problem constants (fixed by setup_inputs): lfi [B,A,H,W,C], f_maps [B,H,W,F]
#define BB 4
#define AA 9
#define HH 256
#define WW 256
#define CC 9
#define FF 64

// ---------------------------------------------------------------------------
// Kernel 1 (round-1 verbatim, proven): hv[b,w,f] = mean_h f_maps[b,h,w,f]
// Block per (b,w): 256 threads = 4 h-lanes x 64 f; 256B/wave contiguous loads.
// ---------------------------------------------------------------------------
__global__ __launch_bounds__(256) void k_hv(const float* __restrict__ fm,
                                            float* __restrict__ hv) {
    const int blk = blockIdx.x;       // b*WW + w
    const int b = blk >> 8;           // WW == 256
    const int w = blk & 255;
    const int f = threadIdx.x & 63;
    const int hl = threadIdx.x >> 6;  // 0..3

    const float* base = fm + (((size_t)b * HH) * WW + w) * FF + f;
    float s = 0.f;
#pragma unroll 8
    for (int h = hl; h < HH; h += 4) {
        s += base[(size_t)h * WW * FF];
    }
    __shared__ float sm[256];
    sm[threadIdx.x] = s;
    __syncthreads();
    if (hl == 0) {
        float t = sm[f] + sm[64 + f] + sm[128 + f] + sm[192 + f];
        hv[(size_t)blk * FF + f] = t * (1.0f / HH);
    }
}

// ---------------------------------------------------------------------------
// Kernel 2 (fused m+out, block per (b,h)):
//  Step A: per-block redundant inv: threads (f=t&63, q=t>>6) scan the
//    q-th quarter of w for max of hv[b,w,f] (L2-resident, 256B/instr
//    f-contiguous); 4 partials -> LDS. 64KB L2 reads/block ~= 2us aggregate.
//  Step B: m[w=t] via round-8's proven window pattern: per a, load the 3
//    overlapping float4s covering floats [9t, 9t+9), branchless head/tail
//    trim (r = t&3 since 9 = 1 mod 4), 9 loads in flight -> m_lds.
//  Step C: round-5's proven store pattern: thread owns f4 = t&15 with
//    hvn float4 from LDS; 16 stores at ob[k*256+t] = 1KB/wave contiguous.
// Race-free: hv is written by the PREVIOUS dispatch; this kernel only reads.
// ---------------------------------------------------------------------------
__global__ __launch_bounds__(256) void k_mout(const float* __restrict__ lfi,
                                              const float* __restrict__ hv,
                                              float4* __restrict__ out) {
    const int t = threadIdx.x;
    const int bh = blockIdx.x;  // b*HH + h
    const int b = bh >> 8;
    const int h = bh & 255;

    __shared__ float sm_max[4][FF];
    __shared__ float hvn_lds[FF];
    __shared__ float m_lds[WW];

    // ---- Step A: partial max over this thread's w-quarter ----
    {
        const int f = t & 63, q = t >> 6;
        const float* hb = hv + (size_t)b * WW * FF + f;
        float mx = -1e30f;
#pragma unroll 8
        for (int j = 0; j < 64; ++j)
            mx = fmaxf(mx, hb[(size_t)(q * 64 + j) * FF]);
        sm_max[q][f] = mx;
    }

    // ---- Step B: angular mean for w = t (round-8 window pattern) ----
    {
        const int r = t & 3;
        const size_t astride4 = (size_t)HH * WW * CC / 4;  // 147456 float4
        const float4* base = (const float4*)lfi + (size_t)b * AA * astride4 +
                             (size_t)h * 576 + ((9 * t) >> 2);
        float acc = 0.f;
#pragma unroll 3
        for (int a = 0; a < AA; ++a) {
            const float4* p = base + (size_t)a * astride4;
            const float4 v0 = p[0], v1 = p[1], v2 = p[2];
            const float s12 = ((v0.x + v0.y) + (v0.z + v0.w)) +
                              ((v1.x + v1.y) + (v1.z + v1.w)) +
                              ((v2.x + v2.y) + (v2.z + v2.w));
            const float head = (r > 0 ? v0.x : 0.f) + (r > 1 ? v0.y : 0.f) +
                               (r > 2 ? v0.z : 0.f);
            const float tail = (r < 1 ? v2.y : 0.f) + (r < 2 ? v2.z : 0.f) +
                               (r < 3 ? v2.w : 0.f);
            acc += s12 - head - tail;
        }
        m_lds[t] = acc * (1.0f / (AA * CC));
    }
    __syncthreads();

    // ---- finalize hvn[f] = hv[b,h,f] / max_w hv[b,w,f] ----
    if (t < FF) {
        const float mx = fmaxf(fmaxf(sm_max[0][t], sm_max[1][t]),
                               fmaxf(sm_max[2][t], sm_max[3][t]));
        hvn_lds[t] = hv[(size_t)bh * FF + t] / mx;
    }
    __syncthreads();

    // ---- Step C: write out row (b,h): 4096 float4, 16 per thread ----
    const int f4 = t & 15;
    const float4 hvn = ((const float4*)hvn_lds)[f4];
    float4* ob = out + (size_t)bh * (WW * FF / 4);
#pragma unroll
    for (int k = 0; k < 16; ++k) {
        const float mv = m_lds[k * 16 + (t >> 4)];  // broadcast per 16 lanes
        float4 o;
        o.x = mv * hvn.x; o.y = mv * hvn.y; o.z = mv * hvn.z; o.w = mv * hvn.w;
        ob[k * 256 + t] = o;
    }
}

extern "C" void kernel_launch(void* const* d_in, const int* in_sizes, int n_in,
                              void* d_out, int out_size, void* d_ws, size_t ws_size,
                              hipStream_t stream) {
    const float* lfi = (const float*)d_in[0];  // [B,A,H,W,C] f32
    const float* fm  = (const float*)d_in[1];  // [B,H,W,F]   f32
    float* out = (float*)d_out;                // [B,H,W,F]   f32

    // Workspace: hv 256KB
    float* hv = (float*)d_ws;

    // 1) column means of f_maps
    k_hv<<<BB * WW, 256, 0, stream>>>(fm, hv);
    // 2) fused: per-block inv + angular mean + output row write
    k_mout<<<BB * HH, 256, 0, stream>>>(lfi, hv, (float4*)out);
}

// Round 11
// 42.438 us; speedup vs baseline: 1.1564x; 1.1564x over previous
//
#include <hip/hip_runtime.h>

// Problem constants (fixed by setup_inputs): lfi [B,A,H,W,C], f_maps [B,H,W,F]
#define BB 4
#define AA 9
#define HH 256
#define WW 256
#define CC 9
#define FF 64

// ---------------------------------------------------------------------------
// Kernel 1 v2: hv[b,w,f] = mean_h f_maps[b,h,w,f]
// Block per (b, w-quad): 256 threads = 4 h-lanes (hl) x 4 w (wsub) x 16 f4.
// Every wave load instruction covers 4 consecutive w rows x 256B = 1KB
// CONTIGUOUS (vs round-1's 256B). Each thread: 64 independent float4 loads
// (h = hl, hl+4, ..., unroll 16 -> 16 in flight), one accumulator.
// Grid = 256 blocks = 1/CU; ILP (not occupancy) hides latency.
// ---------------------------------------------------------------------------
__global__ __launch_bounds__(256) void k_hv(const float* __restrict__ fm,
                                            float* __restrict__ hv) {
    const int t = threadIdx.x;
    const int wq = blockIdx.x & 63;   // 64 w-quads per batch
    const int b = blockIdx.x >> 6;
    const int f4 = t & 15;
    const int wsub = (t >> 4) & 3;
    const int hl = t >> 6;            // 0..3
    const int w = wq * 4 + wsub;

    const float4* base = (const float4*)fm +
                         ((size_t)(b * HH + hl) * WW + w) * (FF / 4) + f4;
    const size_t hstep = (size_t)4 * WW * (FF / 4);  // 4 h-rows of float4
    float4 acc = make_float4(0.f, 0.f, 0.f, 0.f);
#pragma unroll 16
    for (int i = 0; i < 64; ++i) {    // h = hl + 4*i
        float4 v = base[i * hstep];
        acc.x += v.x; acc.y += v.y; acc.z += v.z; acc.w += v.w;
    }

    __shared__ float4 sm[4][64];      // [hl][wsub*16+f4]
    sm[hl][wsub * 16 + f4] = acc;
    __syncthreads();
    if (t < 64) {                     // t = wsub*16 + f4
        const float4 s0 = sm[0][t], s1 = sm[1][t], s2 = sm[2][t], s3 = sm[3][t];
        float4 r;
        r.x = ((s0.x + s1.x) + (s2.x + s3.x)) * (1.0f / HH);
        r.y = ((s0.y + s1.y) + (s2.y + s3.y)) * (1.0f / HH);
        r.z = ((s0.z + s1.z) + (s2.z + s3.z)) * (1.0f / HH);
        r.w = ((s0.w + s1.w) + (s2.w + s3.w)) * (1.0f / HH);
        ((float4*)hv)[(size_t)(b * WW + wq * 4 + (t >> 4)) * (FF / 4) + (t & 15)] = r;
    }
}

// ---------------------------------------------------------------------------
// Kernel 2 (round-9 verbatim, proven): m[b,h,w] = mean_{a,c} lfi[b,a,h,w,c]
// + inv rider blocks (round-1 k_inv body as 4 waves/block over 64 blocks).
// ---------------------------------------------------------------------------
__global__ __launch_bounds__(256) void k_m(const float* __restrict__ lfi,
                                           const float* __restrict__ hv,
                                           float* __restrict__ m,
                                           float* __restrict__ inv) {
    const int t = threadIdx.x;
    if (blockIdx.x < 1024) {
        const int k = blockIdx.x * 256 + t;  // b*65536 + h*256 + w
        const int b = k >> 16;               // HH*WW == 65536
        const int blk_local = blockIdx.x & 255;
        const int r = t & 3;                 // window start within 12 floats
        const size_t astride4 = (size_t)HH * WW * CC / 4;  // 147456 float4

        const float4* base = (const float4*)lfi + (size_t)b * AA * astride4 +
                             (size_t)blk_local * 576 + ((9 * t) >> 2);
        float acc = 0.f;
#pragma unroll 3
        for (int a = 0; a < AA; ++a) {
            const float4* p = base + (size_t)a * astride4;
            const float4 v0 = p[0], v1 = p[1], v2 = p[2];
            // w0..w11 = v0.xyzw v1.xyzw v2.xyzw; want sum of w[r..r+8]
            const float s12 = ((v0.x + v0.y) + (v0.z + v0.w)) +
                              ((v1.x + v1.y) + (v1.z + v1.w)) +
                              ((v2.x + v2.y) + (v2.z + v2.w));
            const float head = (r > 0 ? v0.x : 0.f) + (r > 1 ? v0.y : 0.f) +
                               (r > 2 ? v0.z : 0.f);
            const float tail = (r < 1 ? v2.y : 0.f) + (r < 2 ? v2.z : 0.f) +
                               (r < 3 ? v2.w : 0.f);
            acc += s12 - head - tail;
        }
        m[k] = acc * (1.0f / (AA * CC));
    } else {
        // inv role: wave = one (b,f) pair, round-1 k_inv body verbatim
        const int rb = blockIdx.x - 1024;    // 0..63
        const int wave = t >> 6;             // 0..3
        const int lane = t & 63;
        const int pair = rb * 4 + wave;      // 0..255
        const int b = pair >> 6;
        const int f = pair & 63;
        float mx = -1e30f;
#pragma unroll
        for (int j = 0; j < 4; ++j) {
            mx = fmaxf(mx, hv[((size_t)b * WW + (lane + 64 * j)) * FF + f]);
        }
#pragma unroll
        for (int off = 32; off; off >>= 1)
            mx = fmaxf(mx, __shfl_xor(mx, off));
        if (lane == 0) inv[pair] = 1.0f / mx;
    }
}

// ---------------------------------------------------------------------------
// Kernel 3 (round-9 verbatim, proven): out = m * hv[b,h,f] * inv[b,f]
// One thread per float4 along f; contiguous 16B/lane stores.
// ---------------------------------------------------------------------------
__global__ __launch_bounds__(256) void k_out(const float* __restrict__ m,
                                             const float* __restrict__ hv,
                                             const float* __restrict__ inv,
                                             float4* __restrict__ out) {
    const int idx = blockIdx.x * 256 + threadIdx.x;  // over B*H*W*F/4
    const int f4 = idx & 15;                         // FF/4 == 16
    const int rest = idx >> 4;                       // b*HH*WW + h*WW + w
    const int h = (rest >> 8) & 255;
    const int b = rest >> 16;

    const float mv = m[rest];
    const float4 hv4 = ((const float4*)hv)[((size_t)(b * HH + h)) * (FF / 4) + f4];
    const float4 iv4 = ((const float4*)inv)[b * (FF / 4) + f4];

    float4 o;
    o.x = mv * hv4.x * iv4.x;
    o.y = mv * hv4.y * iv4.y;
    o.z = mv * hv4.z * iv4.z;
    o.w = mv * hv4.w * iv4.w;
    out[idx] = o;
}

extern "C" void kernel_launch(void* const* d_in, const int* in_sizes, int n_in,
                              void* d_out, int out_size, void* d_ws, size_t ws_size,
                              hipStream_t stream) {
    const float* lfi = (const float*)d_in[0];  // [B,A,H,W,C] f32
    const float* fm  = (const float*)d_in[1];  // [B,H,W,F]   f32
    float* out = (float*)d_out;                // [B,H,W,F]   f32

    // Workspace layout (as round 1): hv 256KB | inv 1KB | m 1MB
    char* ws = (char*)d_ws;
    float* hv  = (float*)ws;
    float* inv = (float*)(ws + (size_t)BB * WW * FF * 4);
    float* m   = (float*)(ws + (size_t)BB * WW * FF * 4 + 1024);

    // 1) column means of f_maps (1KB/instr contiguous, deep ILP)
    k_hv<<<BB * 64, 256, 0, stream>>>(fm, hv);
    // 2) angular mean of lfi + inv rider blocks
    k_m<<<1024 + 64, 256, 0, stream>>>(lfi, hv, m, inv);
    // 3) broadcast-multiply into out
    k_out<<<(BB * HH * WW * FF / 4) / 256, 256, 0, stream>>>(m, hv, inv,
                                                             (float4*)out);
}